// Round 16
// baseline (404.720 us; speedup 1.0000x reference)
//
#include <hip/hip_runtime.h>
#include <hip/hip_bf16.h>

// ---------------------------------------------------------------------------
// REMSA fused block on MI355X.
// Shapes: B=4, N=4096, C=1024, H=16, D=64. M = B*N = 16384.
//
//   xb    = bf16(x)                                   [M,1024]
//   W2    = conv_w @ pw_w^T (prefused), b2 fused      [1024,1024]
//   qkvx  = xb @ [qkv_w | W2] + [qkv_b | b2]          [M,4096]  (gemmBG)
//   attn / depthwise3 epilogue (one kernel)           -> xcat [M,2048]
//   out   = xcat @ [out_w; tok_w] + (out_b+tok_b)     [M,1024]  (gemmBG K=2048)
//
// gemmBG: B-operand BYPASSES LDS (loaded global->reg; panels are L2-resident),
// halving the LDS read traffic that round-15 analysis showed rivals MFMA time.
// 256x256 tile, BK=32, 8 waves (2Mx4N), per-wave 128x64.  LDS = 3 bufs x
// 16 KB (A tiles only).  Per tile t: stage A(t+2) via global_load_lds (2/thr),
// load B(t+1) frags into the spare named reg set (4 dwordx4/wave), 8
// ds_read_b128 for A(t), 32 MFMA with current B set, ONE barrier.  No asm
// vmcnt in the loop: A(t+1) DMAs are issued BEFORE bfr(t)'s loads (tile t-1),
// so the compiler's own pre-MFMA vmcnt wait for bfr(t) drains A(t+1) per-wave;
// the fenced barrier makes it block-wide.  A-side bank swizzle unchanged
// (kc ^= (row>>1)&3 on source + kidx on reads; 0 conflicts, rounds 4-15).
// B global addresses use the UNswizzled k-offset (lane>>4)*8 — the two XORs
// cancel, delivering bit-identical fragments to the LDS path.
// ---------------------------------------------------------------------------

typedef __attribute__((ext_vector_type(8))) short sh8;
typedef __attribute__((ext_vector_type(4))) float f4;

__device__ __forceinline__ float bf2f(short s) {
  unsigned u = ((unsigned)(unsigned short)s) << 16;
  return __builtin_bit_cast(float, u);
}
__device__ __forceinline__ short f2bf(float f) {
  return __builtin_bit_cast(short, __float2bfloat16(f));
}
__device__ __forceinline__ void g2l16(const void* g, void* l) {
  __builtin_amdgcn_global_load_lds(
      (const __attribute__((address_space(1))) unsigned int*)g,
      (__attribute__((address_space(3))) unsigned int*)l, 16, 0, 0);
}

// ---------------- f32 -> bf16 convert (x, conv_w, pw_w in one) -------------
__global__ __launch_bounds__(256) void cvt3(
    const float* __restrict__ x, const float* __restrict__ conv_w,
    const float* __restrict__ pw_w, short* __restrict__ xb,
    short* __restrict__ convb, short* __restrict__ pwb) {
  int i = blockIdx.x * 256 + threadIdx.x;  // 9216*256 = 2359296 chunks
  const float* src;
  short* dst;
  int off;
  if (i < 2097152) {
    src = x; dst = xb; off = i;
  } else if (i < 2228224) {
    src = conv_w; dst = convb; off = i - 2097152;
  } else {
    src = pw_w; dst = pwb; off = i - 2228224;
  }
  float4 a = ((const float4*)src)[off * 2];
  float4 b = ((const float4*)src)[off * 2 + 1];
  sh8 o;
  o[0] = f2bf(a.x); o[1] = f2bf(a.y); o[2] = f2bf(a.z); o[3] = f2bf(a.w);
  o[4] = f2bf(b.x); o[5] = f2bf(b.y); o[6] = f2bf(b.z); o[7] = f2bf(b.w);
  ((sh8*)dst)[off] = o;
}

// ------------------- transpose f32 (KxN) -> bf16 (N x ldd) -----------------
__global__ __launch_bounds__(256) void transpose_f32_bf16(
    const float* __restrict__ src, short* __restrict__ dst,
    int N, int ldd, int coff) {
  __shared__ float tile[32][33];
  int kb = blockIdx.y * 32, nb = blockIdx.x * 32;
  int tx = threadIdx.x, ty = threadIdx.y;
#pragma unroll
  for (int j = 0; j < 32; j += 8)
    tile[ty + j][tx] = src[(size_t)(kb + ty + j) * N + nb + tx];
  __syncthreads();
#pragma unroll
  for (int j = 0; j < 32; j += 8)
    dst[(size_t)(nb + ty + j) * ldd + coff + kb + tx] = f2bf(tile[tx][ty + j]);
}

// ------------- transpose out_w (z=0) and tok_w (z=1) into wcatT ------------
__global__ __launch_bounds__(256) void transpose2(
    const float* __restrict__ out_w, const float* __restrict__ tok_w,
    short* __restrict__ dst) {
  __shared__ float tile[32][33];
  const float* src = blockIdx.z ? tok_w : out_w;
  int coff = blockIdx.z ? 1024 : 0;
  int kb = blockIdx.y * 32, nb = blockIdx.x * 32;
  int tx = threadIdx.x, ty = threadIdx.y;
#pragma unroll
  for (int j = 0; j < 32; j += 8)
    tile[ty + j][tx] = src[(size_t)(kb + ty + j) * 1024 + nb + tx];
  __syncthreads();
#pragma unroll
  for (int j = 0; j < 32; j += 8)
    dst[(size_t)(nb + ty + j) * 2048 + coff + kb + tx] = f2bf(tile[tx][ty + j]);
}

// --------------------------- misc bias / dw prep ---------------------------
__global__ __launch_bounds__(256) void prep_misc(
    const float* __restrict__ pw_w, const float* __restrict__ conv_b,
    const float* __restrict__ pw_b, const float* __restrict__ qkv_b,
    const float* __restrict__ out_b, const float* __restrict__ tok_b,
    const float* __restrict__ dw_w, const float* __restrict__ dw_b,
    float* __restrict__ bias4, float* __restrict__ bcat,
    float* __restrict__ dw0, float* __restrict__ dw1,
    float* __restrict__ dw2, float* __restrict__ dwb) {
  int o = blockIdx.x;
  if (o < 1024) {
    float part = 0.f;
    for (int i = threadIdx.x; i < 1024; i += 256)
      part += pw_w[(size_t)o * 1024 + i] * conv_b[i];
#pragma unroll
    for (int off = 32; off >= 1; off >>= 1) part += __shfl_down(part, off);
    __shared__ float red[4];
    int wid = threadIdx.x >> 6, lane = threadIdx.x & 63;
    if (lane == 0) red[wid] = part;
    __syncthreads();
    if (threadIdx.x == 0) {
      float s = red[0] + red[1] + red[2] + red[3];
      bias4[3072 + o] = s + pw_b[o];
      bcat[o] = out_b[o] + tok_b[o];
      dw0[o] = dw_w[o * 3 + 0];
      dw1[o] = dw_w[o * 3 + 1];
      dw2[o] = dw_w[o * 3 + 2];
      dwb[o] = dw_b[o];
    }
  }
  if (threadIdx.x == 0) bias4[o] = qkv_b[o];
}

// --------------------- bf16 GEMM, 128x128 (prep only) ----------------------
template <int OUT_BF16>
__global__ __launch_bounds__(256, 2) void gemm128(
    const short* __restrict__ A, const short* __restrict__ Bt,
    void* __restrict__ Cp, const float* __restrict__ bias, int K, int ldc) {
  __shared__ short As[128 * 32];
  __shared__ short Bs[128 * 32];
  const int wid = threadIdx.x >> 6, lane = threadIdx.x & 63;
  const int bm = blockIdx.y, bn = blockIdx.x;
  const int wr = wid >> 1, wc = wid & 1;
  const size_t abase = (size_t)bm * 128 * K;
  const size_t bbase = (size_t)bn * 128 * K;
  const int r16 = lane & 15, ko = (lane >> 4) * 8;

  f4 acc[4][4] = {};

  for (int k0 = 0; k0 < K; k0 += 32) {
    __syncthreads();
#pragma unroll
    for (int c = 0; c < 2; ++c) {
      int ch = c * 256 + wid * 64 + lane;
      int row = ch >> 2, kc = (ch & 3) * 8;
      g2l16(A + abase + (size_t)row * K + k0 + kc, &As[ch * 8]);
      g2l16(Bt + bbase + (size_t)row * K + k0 + kc, &Bs[ch * 8]);
    }
    __syncthreads();
    sh8 af[4], bf[4];
#pragma unroll
    for (int i = 0; i < 4; ++i)
      af[i] = *(const sh8*)&As[(wr * 64 + i * 16 + r16) * 32 + ko];
#pragma unroll
    for (int j = 0; j < 4; ++j)
      bf[j] = *(const sh8*)&Bs[(wc * 64 + j * 16 + r16) * 32 + ko];
#pragma unroll
    for (int i = 0; i < 4; ++i)
#pragma unroll
      for (int j = 0; j < 4; ++j)
        acc[i][j] = __builtin_amdgcn_mfma_f32_16x16x32_bf16(af[i], bf[j],
                                                            acc[i][j], 0, 0, 0);
  }

  const int crow = wr * 64 + (lane >> 4) * 4;
  const int ccol = wc * 64 + r16;
#pragma unroll
  for (int i = 0; i < 4; ++i) {
#pragma unroll
    for (int j = 0; j < 4; ++j) {
      int col = bn * 128 + ccol + j * 16;
      float bv = bias ? bias[col] : 0.f;
#pragma unroll
      for (int r = 0; r < 4; ++r) {
        int row = bm * 128 + crow + i * 16 + r;
        float v = acc[i][j][r] + bv;
        if (OUT_BF16)
          ((short*)Cp)[(size_t)row * ldc + col] = f2bf(v);
        else
          ((float*)Cp)[(size_t)row * ldc + col] = v;
      }
    }
  }
}

// -------------- bf16 GEMM, 256x256, B-from-global, A-in-LDS ----------------
// C[M,N] = A[M,K] @ Bt[N,K]^T + bias.  Grid 1D, nwg % 8 == 0 (XCD swizzle).
// 512 threads = 8 waves (2M x 4N), per-wave 128x64 (8x4 16x16 frags).
// LDS: 3 bufs x 8192 shorts (A 256x32 tiles).  BK=32, NT=K/32 (even, >=4).
template <int OUT_BF16>
__global__ __launch_bounds__(512, 2) void gemmBG(
    const short* __restrict__ A, const short* __restrict__ Bt,
    void* __restrict__ Cp, const float* __restrict__ bias,
    int K, int ldc, int nbn) {
  __shared__ short lds[24576];  // 48 KiB: 3 bufs x 8192 shorts
  const int tid = threadIdx.x;
  const int lane = tid & 63, wid = tid >> 6;
  const int wr = wid >> 2, wc = wid & 3;
  const int r16 = lane & 15;
  const int kidx = ((lane >> 4) ^ ((r16 >> 1) & 3)) << 3;

  // XCD-aware swizzle (nwg % 8 == 0)
  const int cpx = gridDim.x >> 3;
  const int swz = (blockIdx.x & 7) * cpx + (blockIdx.x >> 3);
  const int bm = swz / nbn, bn = swz % nbn;

  const short* Ag = A + (size_t)bm * 256 * K;
  // B fragment base: row (bn*256 + wc*64 + j*16 + r16), logical k-chunk lane>>4
  const short* Bbase =
      Bt + (size_t)(bn * 256 + wc * 64 + r16) * K + (lane >> 4) * 8;

  // A staging: 1024 16B chunks, 2 per thread, kc-swizzled source
  int gA0, lA0, gA1, lA1;
  {
    int c0 = tid, r0 = c0 >> 2, k0 = (c0 & 3) ^ ((r0 >> 1) & 3);
    gA0 = r0 * K + k0 * 8;
    lA0 = c0 * 8;
    int c1 = 512 + tid, r1 = c1 >> 2, k1 = (c1 & 3) ^ ((r1 >> 1) & 3);
    gA1 = r1 * K + k1 * 8;
    lA1 = c1 * 8;
  }

  f4 acc[8][4] = {};
  const int NT = K >> 5;  // BK = 32

#define STAGE_A(KT, BUF)                                    \
  do {                                                      \
    short* lb = &lds[(BUF) * 8192];                         \
    const short* ga = Ag + (KT) * 32;                       \
    g2l16(ga + gA0, lb + lA0);                              \
    g2l16(ga + gA1, lb + lA1);                              \
  } while (0)

#define LOADB(BF, KT)                                                     \
  do {                                                                    \
    _Pragma("unroll")                                                     \
    for (int j = 0; j < 4; ++j)                                           \
      BF[j] = *(const sh8*)(Bbase + (size_t)j * 16 * K + (KT) * 32);      \
  } while (0)

#define LOADA(BUF)                                                        \
  do {                                                                    \
    const short* buf_ = &lds[(BUF) * 8192];                               \
    _Pragma("unroll")                                                     \
    for (int i = 0; i < 8; ++i)                                           \
      af[i] = *(const sh8*)&buf_[(wr * 128 + i * 16 + r16) * 32 + kidx];  \
  } while (0)

#define MFMA32(BF)                                                        \
  do {                                                                    \
    __builtin_amdgcn_s_setprio(1);                                        \
    _Pragma("unroll")                                                     \
    for (int i = 0; i < 8; ++i)                                           \
      _Pragma("unroll")                                                   \
      for (int j = 0; j < 4; ++j)                                         \
        acc[i][j] = __builtin_amdgcn_mfma_f32_16x16x32_bf16(              \
            af[i], BF[j], acc[i][j], 0, 0, 0);                            \
    __builtin_amdgcn_s_setprio(0);                                        \
  } while (0)

#define BARRIER_FENCED()                                    \
  do {                                                      \
    __builtin_amdgcn_sched_barrier(0);                      \
    __builtin_amdgcn_s_barrier();                           \
    __builtin_amdgcn_sched_barrier(0);                      \
  } while (0)

  sh8 af[8], bfrA[4], bfrB[4];

  // prologue: A(0), A(1) staged; A(0) landed block-wide; then B(0) -> bfrA.
  STAGE_A(0, 0);
  STAGE_A(1, 1);
  __builtin_amdgcn_sched_barrier(0);
  asm volatile("s_waitcnt vmcnt(2)" ::: "memory");  // A(0) landed (A(1) fly)
  BARRIER_FENCED();
  LOADB(bfrA, 0);

  for (int t = 0; t < NT; t += 2) {
    // ---- even tile t: MFMA with bfrA; prefetch B(t+1)->bfrB, A(t+2) -------
    {
      const int kt2 = (t + 2 < NT) ? t + 2 : 0;  // dummy tail reload
      STAGE_A(kt2, (t + 2) % 3);                 // issued BEFORE next B loads
      const int kt1 = (t + 1 < NT) ? t + 1 : 0;
      LOADB(bfrB, kt1);
      LOADA(t % 3);
      MFMA32(bfrA);  // compiler's bfrA-wait drains A(t+1) (older) per-wave
      BARRIER_FENCED();
    }
    // ---- odd tile t+1: MFMA with bfrB; prefetch B(t+2)->bfrA, A(t+3) ------
    {
      const int kt3 = (t + 3 < NT) ? t + 3 : 0;
      STAGE_A(kt3, (t + 3) % 3);
      const int kt2 = (t + 2 < NT) ? t + 2 : 0;
      LOADB(bfrA, kt2);
      LOADA((t + 1) % 3);
      MFMA32(bfrB);  // compiler's bfrB-wait drains A(t+2) (older) per-wave
      BARRIER_FENCED();
    }
  }
#undef STAGE_A
#undef LOADB
#undef LOADA
#undef MFMA32
#undef BARRIER_FENCED

  // C-write: j innermost -> contiguous 128B (bf16) / 256B (f32) per row.
  const int crow0 = bm * 256 + wr * 128 + (lane >> 4) * 4;
  const int ccol0 = bn * 256 + wc * 64 + r16;
  float bv[4];
#pragma unroll
  for (int j = 0; j < 4; ++j) bv[j] = bias ? bias[ccol0 + j * 16] : 0.f;
#pragma unroll
  for (int i = 0; i < 8; ++i) {
#pragma unroll
    for (int r = 0; r < 4; ++r) {
      size_t rowoff = (size_t)(crow0 + i * 16 + r) * ldc + ccol0;
#pragma unroll
      for (int j = 0; j < 4; ++j) {
        float v = acc[i][j][r] + bv[j];
        if (OUT_BF16)
          ((short*)Cp)[rowoff + j * 16] = f2bf(v);
        else
          ((float*)Cp)[rowoff + j * 16] = v;
      }
    }
  }
}

// ------------------ fused epilogue: attention + depthwise ------------------
__global__ __launch_bounds__(256) void epilogue(
    const short* __restrict__ qkvx, const float* __restrict__ pos_bias,
    const float* __restrict__ dw0, const float* __restrict__ dw1,
    const float* __restrict__ dw2, const float* __restrict__ dwb,
    short* __restrict__ xcat) {
  __shared__ short sq[4 * 3072];      // 4 tokens x cols 0-3071
  __shared__ short slice[6 * 1024];   // rows t0-1..t0+4 x cols 3072-4095
  int t0 = blockIdx.x * 4;
#pragma unroll
  for (int c = 0; c < 6; ++c) {
    int g = c * 256 + threadIdx.x;    // 1536 chunks = 4 tok x 384
    int tok = (g * 683) >> 18;        // g / 384 for g < 1536
    int off = g - tok * 384;
    ((sh8*)sq)[tok * 384 + off] =
        *(const sh8*)(qkvx + (size_t)(t0 + tok) * 4096 + off * 8);
  }
#pragma unroll
  for (int s = 0; s < 3; ++s) {
    int g = s * 256 + threadIdx.x;    // 768 chunks = 6 rows x 128
    int r = g >> 7, off = g & 127;
    int gr = t0 - 1 + r;
    sh8 v = {};
    if (gr >= 0 && gr < 16384)
      v = *(const sh8*)(qkvx + (size_t)gr * 4096 + 3072 + off * 8);
    ((sh8*)slice)[g] = v;
  }
  __syncthreads();

  int wid = threadIdx.x >> 6, lane = threadIdx.x & 63;
  int t = t0 + wid, n = t & 4095;
  int h = lane >> 2, sub = lane & 3;
  const short* base = sq + wid * 3072 + h * 192;

  float qf[64];
#pragma unroll
  for (int c = 0; c < 8; ++c) {
    sh8 v8 = *(const sh8*)(base + c * 8);
#pragma unroll
    for (int j = 0; j < 8; ++j) qf[c * 8 + j] = bf2f(v8[j]);
  }

  const float* pb = pos_bias + (size_t)n * 256 + h * 16 + sub * 4;
  float p[4];
  float m = -1e30f;
#pragma unroll
  for (int g4 = 0; g4 < 4; ++g4) {
    int g = sub * 4 + g4;
    const short* kk = sq + wid * 3072 + g * 192 + 64;
    float acc = 0.f;
#pragma unroll
    for (int c = 0; c < 8; ++c) {
      sh8 k8 = *(const sh8*)(kk + c * 8);
#pragma unroll
      for (int j = 0; j < 8; ++j) acc += qf[c * 8 + j] * bf2f(k8[j]);
    }
    p[g4] = acc * 0.125f + pb[g4];
    m = fmaxf(m, p[g4]);
  }
  m = fmaxf(m, __shfl_xor(m, 1));
  m = fmaxf(m, __shfl_xor(m, 2));
  float sum = 0.f;
#pragma unroll
  for (int g4 = 0; g4 < 4; ++g4) {
    p[g4] = __expf(p[g4] - m);
    sum += p[g4];
  }
  sum += __shfl_xor(sum, 1);
  sum += __shfl_xor(sum, 2);
  float inv = 1.0f / sum;
#pragma unroll
  for (int g4 = 0; g4 < 4; ++g4) p[g4] *= inv;

  float pall[16];
#pragma unroll
  for (int g = 0; g < 16; ++g)
    pall[g] = __shfl(p[g & 3], (lane & 60) | (g >> 2));

  float o[16] = {};
#pragma unroll
  for (int g = 0; g < 16; ++g) {
    const short* vv = sq + wid * 3072 + g * 192 + 128 + sub * 16;
    sh8 va = *(const sh8*)vv;
    sh8 vb = *(const sh8*)(vv + 8);
#pragma unroll
    for (int j = 0; j < 8; ++j) {
      o[j] += pall[g] * bf2f(va[j]);
      o[8 + j] += pall[g] * bf2f(vb[j]);
    }
  }
  sh8 oa, ob;
#pragma unroll
  for (int j = 0; j < 8; ++j) {
    oa[j] = f2bf(o[j]);
    ob[j] = f2bf(o[8 + j]);
  }
  short* dst = xcat + (size_t)t * 2048 + h * 64 + sub * 16;
  *(sh8*)dst = oa;
  *(sh8*)(dst + 8) = ob;

#pragma unroll
  for (int it = 0; it < 2; ++it) {
    int w = it * 256 + threadIdx.x;   // 512 = 4 tok x 64 col-chunks
    int tok = w >> 7, co = (w & 127) * 8;
    int tt = t0 + tok, nn = tt & 4095;
    const short* lo8 = slice + tok * 1024 + co;
    const short* mi8 = lo8 + 1024;
    const short* hi8 = lo8 + 2048;
    sh8 lo = (nn > 0) ? *(const sh8*)lo8 : sh8{};
    sh8 mi = *(const sh8*)mi8;
    sh8 hi = (nn < 4095) ? *(const sh8*)hi8 : sh8{};
    sh8 out;
#pragma unroll
    for (int j = 0; j < 8; ++j) {
      float v = dw0[co + j] * bf2f(lo[j]) + dw1[co + j] * bf2f(mi[j]) +
                dw2[co + j] * bf2f(hi[j]) + dwb[co + j];
      out[j] = f2bf(v);
    }
    *(sh8*)(xcat + (size_t)tt * 2048 + 1024 + co) = out;
  }
}

// ---------------------------------------------------------------------------
extern "C" void kernel_launch(void* const* d_in, const int* in_sizes, int n_in,
                              void* d_out, int out_size, void* d_ws,
                              size_t ws_size, hipStream_t stream) {
  const float* x      = (const float*)d_in[0];
  const float* qkv_w  = (const float*)d_in[1];
  const float* qkv_b  = (const float*)d_in[2];
  const float* out_w  = (const float*)d_in[3];
  const float* out_b  = (const float*)d_in[4];
  const float* pos_b  = (const float*)d_in[5];
  const float* conv_w = (const float*)d_in[6];
  const float* conv_b = (const float*)d_in[7];
  const float* pw_w   = (const float*)d_in[8];
  const float* pw_b   = (const float*)d_in[9];
  const float* dw_w   = (const float*)d_in[10];
  const float* dw_b   = (const float*)d_in[11];
  const float* tok_w  = (const float*)d_in[12];
  const float* tok_b  = (const float*)d_in[13];

  const int M = 16384;
  char* ws = (char*)d_ws;
  size_t off = 0;
  auto alloc = [&](size_t bytes) -> void* {
    void* p = ws + off;
    off += (bytes + 255) & ~(size_t)255;
    return p;
  };
  short* xb    = (short*)alloc((size_t)M * 1024 * 2);
  short* wbig  = (short*)alloc((size_t)4096 * 1024 * 2);  // [qkv_w^T | W2^T]
  short* wcatT = (short*)alloc((size_t)1024 * 2048 * 2);
  short* convb = (short*)alloc((size_t)1024 * 1024 * 2);
  short* pwb   = (short*)alloc((size_t)1024 * 1024 * 2);
  short* qkvx  = (short*)alloc((size_t)M * 4096 * 2);
  short* xcat  = (short*)alloc((size_t)M * 2048 * 2);
  float* bias4 = (float*)alloc(4096 * 4);
  float* bcat  = (float*)alloc(1024 * 4);
  float* dw0   = (float*)alloc(1024 * 4);
  float* dw1   = (float*)alloc(1024 * 4);
  float* dw2   = (float*)alloc(1024 * 4);
  float* dwb   = (float*)alloc(1024 * 4);
  (void)ws_size; (void)in_sizes; (void)n_in; (void)out_size;

  // weight prep (consolidated launches)
  cvt3<<<9216, 256, 0, stream>>>(x, conv_w, pw_w, xb, convb, pwb);
  transpose_f32_bf16<<<dim3(96, 32), dim3(32, 8), 0, stream>>>(qkv_w, wbig, 3072, 1024, 0);
  transpose2<<<dim3(32, 32, 2), dim3(32, 8), 0, stream>>>(out_w, tok_w, wcatT);
  prep_misc<<<3072, 256, 0, stream>>>(pw_w, conv_b, pw_b, qkv_b, out_b, tok_b,
                                      dw_w, dw_b, bias4, bcat, dw0, dw1, dw2, dwb);
  // W2^T[o][p] = sum_i pw_w[o][i] * conv_w[p][i] -> rows 3072+ of wbig
  gemm128<1><<<dim3(8, 8), 256, 0, stream>>>(pwb, convb, wbig + (size_t)3072 * 1024,
                                             nullptr, 1024, 1024);

  // fused qkv+conv GEMM: [M,1024] @ [4096,1024]^T -> [M,4096]
  gemmBG<1><<<1024, 512, 0, stream>>>(xb, wbig, qkvx, bias4, 1024, 4096, 16);

  // fused attention + depthwise epilogue
  epilogue<<<4096, 256, 0, stream>>>(qkvx, pos_b, dw0, dw1, dw2, dwb, xcat);

  // out = xcat @ [out_w; tok_w] + (out_b + tok_b)
  gemmBG<0><<<256, 512, 0, stream>>>(xcat, wcatT, d_out, bcat, 2048, 1024, 4);
}

// Round 17
// 318.835 us; speedup vs baseline: 1.2694x; 1.2694x over previous
//
#include <hip/hip_runtime.h>
#include <hip/hip_bf16.h>

// ---------------------------------------------------------------------------
// REMSA fused block on MI355X.  Best-measured composition:
//   - gemm256: round-9 register-dbuf fragments + depth-3 DMA (141 us fused)
//   - prep: round-15 consolidated cvt3 / transpose2
//   - epilogue: round-15 fused attention + depthwise
//
//   xb    = bf16(x)                                   [M,1024]
//   W2    = conv_w @ pw_w^T (prefused), b2 fused      [1024,1024]
//   qkvx  = xb @ [qkv_w | W2] + [qkv_b | b2]          [M,4096]  (gemm256)
//   attn / depthwise3 epilogue (one kernel)           -> xcat [M,2048]
//   out   = xcat @ [out_w; tok_w] + (out_b+tok_b)     [M,1024]  (gemm256 K=2048)
// ---------------------------------------------------------------------------

typedef __attribute__((ext_vector_type(8))) short sh8;
typedef __attribute__((ext_vector_type(4))) float f4;

__device__ __forceinline__ float bf2f(short s) {
  unsigned u = ((unsigned)(unsigned short)s) << 16;
  return __builtin_bit_cast(float, u);
}
__device__ __forceinline__ short f2bf(float f) {
  return __builtin_bit_cast(short, __float2bfloat16(f));
}
__device__ __forceinline__ void g2l16(const void* g, void* l) {
  __builtin_amdgcn_global_load_lds(
      (const __attribute__((address_space(1))) unsigned int*)g,
      (__attribute__((address_space(3))) unsigned int*)l, 16, 0, 0);
}

// ---------------- f32 -> bf16 convert (x, conv_w, pw_w in one) -------------
__global__ __launch_bounds__(256) void cvt3(
    const float* __restrict__ x, const float* __restrict__ conv_w,
    const float* __restrict__ pw_w, short* __restrict__ xb,
    short* __restrict__ convb, short* __restrict__ pwb) {
  int i = blockIdx.x * 256 + threadIdx.x;  // 9216*256 = 2359296 chunks
  const float* src;
  short* dst;
  int off;
  if (i < 2097152) {
    src = x; dst = xb; off = i;
  } else if (i < 2228224) {
    src = conv_w; dst = convb; off = i - 2097152;
  } else {
    src = pw_w; dst = pwb; off = i - 2228224;
  }
  float4 a = ((const float4*)src)[off * 2];
  float4 b = ((const float4*)src)[off * 2 + 1];
  sh8 o;
  o[0] = f2bf(a.x); o[1] = f2bf(a.y); o[2] = f2bf(a.z); o[3] = f2bf(a.w);
  o[4] = f2bf(b.x); o[5] = f2bf(b.y); o[6] = f2bf(b.z); o[7] = f2bf(b.w);
  ((sh8*)dst)[off] = o;
}

// ------------------- transpose f32 (KxN) -> bf16 (N x ldd) -----------------
__global__ __launch_bounds__(256) void transpose_f32_bf16(
    const float* __restrict__ src, short* __restrict__ dst,
    int N, int ldd, int coff) {
  __shared__ float tile[32][33];
  int kb = blockIdx.y * 32, nb = blockIdx.x * 32;
  int tx = threadIdx.x, ty = threadIdx.y;
#pragma unroll
  for (int j = 0; j < 32; j += 8)
    tile[ty + j][tx] = src[(size_t)(kb + ty + j) * N + nb + tx];
  __syncthreads();
#pragma unroll
  for (int j = 0; j < 32; j += 8)
    dst[(size_t)(nb + ty + j) * ldd + coff + kb + tx] = f2bf(tile[tx][ty + j]);
}

// ------------- transpose out_w (z=0) and tok_w (z=1) into wcatT ------------
__global__ __launch_bounds__(256) void transpose2(
    const float* __restrict__ out_w, const float* __restrict__ tok_w,
    short* __restrict__ dst) {
  __shared__ float tile[32][33];
  const float* src = blockIdx.z ? tok_w : out_w;
  int coff = blockIdx.z ? 1024 : 0;
  int kb = blockIdx.y * 32, nb = blockIdx.x * 32;
  int tx = threadIdx.x, ty = threadIdx.y;
#pragma unroll
  for (int j = 0; j < 32; j += 8)
    tile[ty + j][tx] = src[(size_t)(kb + ty + j) * 1024 + nb + tx];
  __syncthreads();
#pragma unroll
  for (int j = 0; j < 32; j += 8)
    dst[(size_t)(nb + ty + j) * 2048 + coff + kb + tx] = f2bf(tile[tx][ty + j]);
}

// --------------------------- misc bias / dw prep ---------------------------
__global__ __launch_bounds__(256) void prep_misc(
    const float* __restrict__ pw_w, const float* __restrict__ conv_b,
    const float* __restrict__ pw_b, const float* __restrict__ qkv_b,
    const float* __restrict__ out_b, const float* __restrict__ tok_b,
    const float* __restrict__ dw_w, const float* __restrict__ dw_b,
    float* __restrict__ bias4, float* __restrict__ bcat,
    float* __restrict__ dw0, float* __restrict__ dw1,
    float* __restrict__ dw2, float* __restrict__ dwb) {
  int o = blockIdx.x;
  if (o < 1024) {
    float part = 0.f;
    for (int i = threadIdx.x; i < 1024; i += 256)
      part += pw_w[(size_t)o * 1024 + i] * conv_b[i];
#pragma unroll
    for (int off = 32; off >= 1; off >>= 1) part += __shfl_down(part, off);
    __shared__ float red[4];
    int wid = threadIdx.x >> 6, lane = threadIdx.x & 63;
    if (lane == 0) red[wid] = part;
    __syncthreads();
    if (threadIdx.x == 0) {
      float s = red[0] + red[1] + red[2] + red[3];
      bias4[3072 + o] = s + pw_b[o];
      bcat[o] = out_b[o] + tok_b[o];
      dw0[o] = dw_w[o * 3 + 0];
      dw1[o] = dw_w[o * 3 + 1];
      dw2[o] = dw_w[o * 3 + 2];
      dwb[o] = dw_b[o];
    }
  }
  if (threadIdx.x == 0) bias4[o] = qkv_b[o];
}

// --------------------- bf16 GEMM, 128x128 (prep only) ----------------------
template <int OUT_BF16>
__global__ __launch_bounds__(256, 2) void gemm128(
    const short* __restrict__ A, const short* __restrict__ Bt,
    void* __restrict__ Cp, const float* __restrict__ bias, int K, int ldc) {
  __shared__ short As[128 * 32];
  __shared__ short Bs[128 * 32];
  const int wid = threadIdx.x >> 6, lane = threadIdx.x & 63;
  const int bm = blockIdx.y, bn = blockIdx.x;
  const int wr = wid >> 1, wc = wid & 1;
  const size_t abase = (size_t)bm * 128 * K;
  const size_t bbase = (size_t)bn * 128 * K;
  const int r16 = lane & 15, ko = (lane >> 4) * 8;

  f4 acc[4][4] = {};

  for (int k0 = 0; k0 < K; k0 += 32) {
    __syncthreads();
#pragma unroll
    for (int c = 0; c < 2; ++c) {
      int ch = c * 256 + wid * 64 + lane;
      int row = ch >> 2, kc = (ch & 3) * 8;
      g2l16(A + abase + (size_t)row * K + k0 + kc, &As[ch * 8]);
      g2l16(Bt + bbase + (size_t)row * K + k0 + kc, &Bs[ch * 8]);
    }
    __syncthreads();
    sh8 af[4], bf[4];
#pragma unroll
    for (int i = 0; i < 4; ++i)
      af[i] = *(const sh8*)&As[(wr * 64 + i * 16 + r16) * 32 + ko];
#pragma unroll
    for (int j = 0; j < 4; ++j)
      bf[j] = *(const sh8*)&Bs[(wc * 64 + j * 16 + r16) * 32 + ko];
#pragma unroll
    for (int i = 0; i < 4; ++i)
#pragma unroll
      for (int j = 0; j < 4; ++j)
        acc[i][j] = __builtin_amdgcn_mfma_f32_16x16x32_bf16(af[i], bf[j],
                                                            acc[i][j], 0, 0, 0);
  }

  const int crow = wr * 64 + (lane >> 4) * 4;
  const int ccol = wc * 64 + r16;
#pragma unroll
  for (int i = 0; i < 4; ++i) {
#pragma unroll
    for (int j = 0; j < 4; ++j) {
      int col = bn * 128 + ccol + j * 16;
      float bv = bias ? bias[col] : 0.f;
#pragma unroll
      for (int r = 0; r < 4; ++r) {
        int row = bm * 128 + crow + i * 16 + r;
        float v = acc[i][j][r] + bv;
        if (OUT_BF16)
          ((short*)Cp)[(size_t)row * ldc + col] = f2bf(v);
        else
          ((float*)Cp)[(size_t)row * ldc + col] = v;
      }
    }
  }
}

// ------- bf16 GEMM, 256x256, register-dbuf fragments + depth-3 DMA ---------
// (round-9 verified: 141 us on the fused shape, MfmaUtil ~44%)
template <int OUT_BF16>
__global__ __launch_bounds__(512, 2) void gemm256(
    const short* __restrict__ A, const short* __restrict__ Bt,
    void* __restrict__ Cp, const float* __restrict__ bias,
    int K, int ldc, int nbn) {
  __shared__ short lds[65536];  // 128 KiB
  const int tid = threadIdx.x;
  const int lane = tid & 63, wid = tid >> 6;
  const int wr = wid >> 2, wc = wid & 3;
  const int r16 = lane & 15;
  const int kidx = ((lane >> 4) ^ ((r16 >> 1) & 3)) << 3;

  // XCD-aware swizzle (nwg % 8 == 0)
  const int cpx = gridDim.x >> 3;
  const int swz = (blockIdx.x & 7) * cpx + (blockIdx.x >> 3);
  const int bm = swz / nbn, bn = swz % nbn;

  const short* Ag = A + (size_t)bm * 256 * K;
  const short* Bg = Bt + (size_t)bn * 256 * K;

  int goff0, goff1, loff0, loff1;
  {
    int s0 = tid, row0 = s0 >> 2;
    int kc0 = (s0 & 3) ^ ((row0 >> 1) & 3);
    goff0 = row0 * K + kc0 * 8;
    loff0 = s0 * 8;
    int s1 = 512 + tid, row1 = s1 >> 2;
    int kc1 = (s1 & 3) ^ ((row1 >> 1) & 3);
    goff1 = row1 * K + kc1 * 8;
    loff1 = s1 * 8;
  }

  f4 acc[8][4] = {};
  const int NT = K >> 5;

#define STAGE_FULL(KT, B)                                   \
  do {                                                      \
    short* lb = &lds[(B) * 16384];                          \
    const short* ga = Ag + (KT) * 32;                       \
    const short* gb = Bg + (KT) * 32;                       \
    g2l16(ga + goff0, lb + loff0);                          \
    g2l16(gb + goff0, lb + 8192 + loff0);                   \
    g2l16(ga + goff1, lb + loff1);                          \
    g2l16(gb + goff1, lb + 8192 + loff1);                   \
  } while (0)

#define LOADFRAG(AF, BF, BUFIDX)                                          \
  do {                                                                    \
    const short* Ab_ = &lds[(BUFIDX) * 16384];                            \
    const short* Bb_ = Ab_ + 8192;                                        \
    _Pragma("unroll")                                                     \
    for (int i = 0; i < 8; ++i)                                           \
      AF[i] = *(const sh8*)&Ab_[(wr * 128 + i * 16 + r16) * 32 + kidx];   \
    _Pragma("unroll")                                                     \
    for (int j = 0; j < 4; ++j)                                           \
      BF[j] = *(const sh8*)&Bb_[(wc * 64 + j * 16 + r16) * 32 + kidx];    \
  } while (0)

#define MFMA_ALL(AF, BF)                                                  \
  do {                                                                    \
    _Pragma("unroll")                                                     \
    for (int i = 0; i < 8; ++i)                                           \
      _Pragma("unroll")                                                   \
      for (int j = 0; j < 4; ++j)                                         \
        acc[i][j] = __builtin_amdgcn_mfma_f32_16x16x32_bf16(              \
            AF[i], BF[j], acc[i][j], 0, 0, 0);                            \
  } while (0)

  // prologue: stage tiles 0,1,2; ensure 0,1 landed block-wide.
  STAGE_FULL(0, 0);
  STAGE_FULL(1, 1);
  STAGE_FULL(2, 2);
  asm volatile("s_waitcnt vmcnt(4)" ::: "memory");
  __builtin_amdgcn_sched_barrier(0);
  __builtin_amdgcn_s_barrier();
  __builtin_amdgcn_sched_barrier(0);

  sh8 afA[8], bfA[4], afB[8], bfB[4];
  LOADFRAG(afA, bfA, 0);  // fragments for tile 0

  for (int t = 0; t < NT; t += 2) {
    // ---- even tile t: compute with A-set, prefetch t+1 into B-set --------
    LOADFRAG(afB, bfB, (t + 1) & 3);
    {
      const int kt = (t + 3 < NT) ? t + 3 : 0;  // dummy reload: uniform ledger
      STAGE_FULL(kt, (t + 3) & 3);
    }
    __builtin_amdgcn_s_setprio(1);
    MFMA_ALL(afA, bfA);
    __builtin_amdgcn_s_setprio(0);
    __builtin_amdgcn_sched_barrier(0);
    asm volatile("s_waitcnt vmcnt(4)" ::: "memory");  // t+2 landed
    __builtin_amdgcn_sched_barrier(0);
    __builtin_amdgcn_s_barrier();
    __builtin_amdgcn_sched_barrier(0);

    // ---- odd tile t+1: compute with B-set, prefetch t+2 into A-set -------
    LOADFRAG(afA, bfA, (t + 2) & 3);
    {
      const int kt = (t + 4 < NT) ? t + 4 : 0;
      STAGE_FULL(kt, (t + 4) & 3);
    }
    __builtin_amdgcn_s_setprio(1);
    MFMA_ALL(afB, bfB);
    __builtin_amdgcn_s_setprio(0);
    __builtin_amdgcn_sched_barrier(0);
    asm volatile("s_waitcnt vmcnt(4)" ::: "memory");  // t+3 landed
    __builtin_amdgcn_sched_barrier(0);
    __builtin_amdgcn_s_barrier();
    __builtin_amdgcn_sched_barrier(0);
  }
#undef STAGE_FULL
#undef LOADFRAG
#undef MFMA_ALL

  // C-write: j innermost -> contiguous 128B (bf16) / 256B (f32) per row.
  const int crow0 = bm * 256 + wr * 128 + (lane >> 4) * 4;
  const int ccol0 = bn * 256 + wc * 64 + r16;
  float bv[4];
#pragma unroll
  for (int j = 0; j < 4; ++j) bv[j] = bias ? bias[ccol0 + j * 16] : 0.f;
#pragma unroll
  for (int i = 0; i < 8; ++i) {
#pragma unroll
    for (int r = 0; r < 4; ++r) {
      size_t rowoff = (size_t)(crow0 + i * 16 + r) * ldc + ccol0;
#pragma unroll
      for (int j = 0; j < 4; ++j) {
        float v = acc[i][j][r] + bv[j];
        if (OUT_BF16)
          ((short*)Cp)[rowoff + j * 16] = f2bf(v);
        else
          ((float*)Cp)[rowoff + j * 16] = v;
      }
    }
  }
}

// ------------------ fused epilogue: attention + depthwise ------------------
__global__ __launch_bounds__(256) void epilogue(
    const short* __restrict__ qkvx, const float* __restrict__ pos_bias,
    const float* __restrict__ dw0, const float* __restrict__ dw1,
    const float* __restrict__ dw2, const float* __restrict__ dwb,
    short* __restrict__ xcat) {
  __shared__ short sq[4 * 3072];      // 4 tokens x cols 0-3071
  __shared__ short slice[6 * 1024];   // rows t0-1..t0+4 x cols 3072-4095
  int t0 = blockIdx.x * 4;
#pragma unroll
  for (int c = 0; c < 6; ++c) {
    int g = c * 256 + threadIdx.x;    // 1536 chunks = 4 tok x 384
    int tok = (g * 683) >> 18;        // g / 384 for g < 1536
    int off = g - tok * 384;
    ((sh8*)sq)[tok * 384 + off] =
        *(const sh8*)(qkvx + (size_t)(t0 + tok) * 4096 + off * 8);
  }
#pragma unroll
  for (int s = 0; s < 3; ++s) {
    int g = s * 256 + threadIdx.x;    // 768 chunks = 6 rows x 128
    int r = g >> 7, off = g & 127;
    int gr = t0 - 1 + r;
    sh8 v = {};
    if (gr >= 0 && gr < 16384)
      v = *(const sh8*)(qkvx + (size_t)gr * 4096 + 3072 + off * 8);
    ((sh8*)slice)[g] = v;
  }
  __syncthreads();

  int wid = threadIdx.x >> 6, lane = threadIdx.x & 63;
  int t = t0 + wid, n = t & 4095;
  int h = lane >> 2, sub = lane & 3;
  const short* base = sq + wid * 3072 + h * 192;

  float qf[64];
#pragma unroll
  for (int c = 0; c < 8; ++c) {
    sh8 v8 = *(const sh8*)(base + c * 8);
#pragma unroll
    for (int j = 0; j < 8; ++j) qf[c * 8 + j] = bf2f(v8[j]);
  }

  const float* pb = pos_bias + (size_t)n * 256 + h * 16 + sub * 4;
  float p[4];
  float m = -1e30f;
#pragma unroll
  for (int g4 = 0; g4 < 4; ++g4) {
    int g = sub * 4 + g4;
    const short* kk = sq + wid * 3072 + g * 192 + 64;
    float acc = 0.f;
#pragma unroll
    for (int c = 0; c < 8; ++c) {
      sh8 k8 = *(const sh8*)(kk + c * 8);
#pragma unroll
      for (int j = 0; j < 8; ++j) acc += qf[c * 8 + j] * bf2f(k8[j]);
    }
    p[g4] = acc * 0.125f + pb[g4];
    m = fmaxf(m, p[g4]);
  }
  m = fmaxf(m, __shfl_xor(m, 1));
  m = fmaxf(m, __shfl_xor(m, 2));
  float sum = 0.f;
#pragma unroll
  for (int g4 = 0; g4 < 4; ++g4) {
    p[g4] = __expf(p[g4] - m);
    sum += p[g4];
  }
  sum += __shfl_xor(sum, 1);
  sum += __shfl_xor(sum, 2);
  float inv = 1.0f / sum;
#pragma unroll
  for (int g4 = 0; g4 < 4; ++g4) p[g4] *= inv;

  float pall[16];
#pragma unroll
  for (int g = 0; g < 16; ++g)
    pall[g] = __shfl(p[g & 3], (lane & 60) | (g >> 2));

  float o[16] = {};
#pragma unroll
  for (int g = 0; g < 16; ++g) {
    const short* vv = sq + wid * 3072 + g * 192 + 128 + sub * 16;
    sh8 va = *(const sh8*)vv;
    sh8 vb = *(const sh8*)(vv + 8);
#pragma unroll
    for (int j = 0; j < 8; ++j) {
      o[j] += pall[g] * bf2f(va[j]);
      o[8 + j] += pall[g] * bf2f(vb[j]);
    }
  }
  sh8 oa, ob;
#pragma unroll
  for (int j = 0; j < 8; ++j) {
    oa[j] = f2bf(o[j]);
    ob[j] = f2bf(o[8 + j]);
  }
  short* dst = xcat + (size_t)t * 2048 + h * 64 + sub * 16;
  *(sh8*)dst = oa;
  *(sh8*)(dst + 8) = ob;

#pragma unroll
  for (int it = 0; it < 2; ++it) {
    int w = it * 256 + threadIdx.x;   // 512 = 4 tok x 64 col-chunks
    int tok = w >> 7, co = (w & 127) * 8;
    int tt = t0 + tok, nn = tt & 4095;
    const short* lo8 = slice + tok * 1024 + co;
    const short* mi8 = lo8 + 1024;
    const short* hi8 = lo8 + 2048;
    sh8 lo = (nn > 0) ? *(const sh8*)lo8 : sh8{};
    sh8 mi = *(const sh8*)mi8;
    sh8 hi = (nn < 4095) ? *(const sh8*)hi8 : sh8{};
    sh8 out;
#pragma unroll
    for (int j = 0; j < 8; ++j) {
      float v = dw0[co + j] * bf2f(lo[j]) + dw1[co + j] * bf2f(mi[j]) +
                dw2[co + j] * bf2f(hi[j]) + dwb[co + j];
      out[j] = f2bf(v);
    }
    *(sh8*)(xcat + (size_t)tt * 2048 + 1024 + co) = out;
  }
}

// ---------------------------------------------------------------------------
extern "C" void kernel_launch(void* const* d_in, const int* in_sizes, int n_in,
                              void* d_out, int out_size, void* d_ws,
                              size_t ws_size, hipStream_t stream) {
  const float* x      = (const float*)d_in[0];
  const float* qkv_w  = (const float*)d_in[1];
  const float* qkv_b  = (const float*)d_in[2];
  const float* out_w  = (const float*)d_in[3];
  const float* out_b  = (const float*)d_in[4];
  const float* pos_b  = (const float*)d_in[5];
  const float* conv_w = (const float*)d_in[6];
  const float* conv_b = (const float*)d_in[7];
  const float* pw_w   = (const float*)d_in[8];
  const float* pw_b   = (const float*)d_in[9];
  const float* dw_w   = (const float*)d_in[10];
  const float* dw_b   = (const float*)d_in[11];
  const float* tok_w  = (const float*)d_in[12];
  const float* tok_b  = (const float*)d_in[13];

  const int M = 16384;
  char* ws = (char*)d_ws;
  size_t off = 0;
  auto alloc = [&](size_t bytes) -> void* {
    void* p = ws + off;
    off += (bytes + 255) & ~(size_t)255;
    return p;
  };
  short* xb    = (short*)alloc((size_t)M * 1024 * 2);
  short* wbig  = (short*)alloc((size_t)4096 * 1024 * 2);  // [qkv_w^T | W2^T]
  short* wcatT = (short*)alloc((size_t)1024 * 2048 * 2);
  short* convb = (short*)alloc((size_t)1024 * 1024 * 2);
  short* pwb   = (short*)alloc((size_t)1024 * 1024 * 2);
  short* qkvx  = (short*)alloc((size_t)M * 4096 * 2);
  short* xcat  = (short*)alloc((size_t)M * 2048 * 2);
  float* bias4 = (float*)alloc(4096 * 4);
  float* bcat  = (float*)alloc(1024 * 4);
  float* dw0   = (float*)alloc(1024 * 4);
  float* dw1   = (float*)alloc(1024 * 4);
  float* dw2   = (float*)alloc(1024 * 4);
  float* dwb   = (float*)alloc(1024 * 4);
  (void)ws_size; (void)in_sizes; (void)n_in; (void)out_size;

  // weight prep (consolidated launches)
  cvt3<<<9216, 256, 0, stream>>>(x, conv_w, pw_w, xb, convb, pwb);
  transpose_f32_bf16<<<dim3(96, 32), dim3(32, 8), 0, stream>>>(qkv_w, wbig, 3072, 1024, 0);
  transpose2<<<dim3(32, 32, 2), dim3(32, 8), 0, stream>>>(out_w, tok_w, wcatT);
  prep_misc<<<3072, 256, 0, stream>>>(pw_w, conv_b, pw_b, qkv_b, out_b, tok_b,
                                      dw_w, dw_b, bias4, bcat, dw0, dw1, dw2, dwb);
  // W2^T[o][p] = sum_i pw_w[o][i] * conv_w[p][i] -> rows 3072+ of wbig
  gemm128<1><<<dim3(8, 8), 256, 0, stream>>>(pwb, convb, wbig + (size_t)3072 * 1024,
                                             nullptr, 1024, 1024);

  // fused qkv+conv GEMM: [M,1024] @ [4096,1024]^T -> [M,4096]
  gemm256<1><<<1024, 512, 0, stream>>>(xb, wbig, qkvx, bias4, 1024, 4096, 16);

  // fused attention + depthwise epilogue
  epilogue<<<4096, 256, 0, stream>>>(qkvx, pos_b, dw0, dw1, dw2, dwb, xcat);

  // out = xcat @ [out_w; tok_w] + (out_b + tok_b)
  gemm256<0><<<256, 512, 0, stream>>>(xcat, wcatT, d_out, bcat, 2048, 1024, 4);
}

// Round 18
// 307.089 us; speedup vs baseline: 1.3179x; 1.0382x over previous
//
#include <hip/hip_runtime.h>
#include <hip/hip_bf16.h>

// ---------------------------------------------------------------------------
// REMSA fused block on MI355X.
//   - gemm256: round-9 register-dbuf fragments + depth-3 DMA (141 us fused)
//   - epilogue: MFMA-based per-token attention (S^T trick) + depthwise
//   - prep: consolidated cvt3 / transpose3
//
//   xb    = bf16(x)                                   [M,1024]
//   W2    = conv_w @ pw_w^T (prefused), b2 fused      [1024,1024]
//   qkvx  = xb @ [qkv_w | W2] + [qkv_b | b2]          [M,4096]  (gemm256)
//   attn / depthwise3 epilogue (one kernel)           -> xcat [M,2048]
//   out   = xcat @ [out_w; tok_w] + (out_b+tok_b)     [M,1024]  (gemm256 K=2048)
// ---------------------------------------------------------------------------

typedef __attribute__((ext_vector_type(8))) short sh8;
typedef __attribute__((ext_vector_type(4))) short sh4;
typedef __attribute__((ext_vector_type(4))) float f4;

__device__ __forceinline__ float bf2f(short s) {
  unsigned u = ((unsigned)(unsigned short)s) << 16;
  return __builtin_bit_cast(float, u);
}
__device__ __forceinline__ short f2bf(float f) {
  return __builtin_bit_cast(short, __float2bfloat16(f));
}
__device__ __forceinline__ void g2l16(const void* g, void* l) {
  __builtin_amdgcn_global_load_lds(
      (const __attribute__((address_space(1))) unsigned int*)g,
      (__attribute__((address_space(3))) unsigned int*)l, 16, 0, 0);
}

// ---------------- f32 -> bf16 convert (x, conv_w, pw_w in one) -------------
__global__ __launch_bounds__(256) void cvt3(
    const float* __restrict__ x, const float* __restrict__ conv_w,
    const float* __restrict__ pw_w, short* __restrict__ xb,
    short* __restrict__ convb, short* __restrict__ pwb) {
  int i = blockIdx.x * 256 + threadIdx.x;  // 9216*256 = 2359296 chunks
  const float* src;
  short* dst;
  int off;
  if (i < 2097152) {
    src = x; dst = xb; off = i;
  } else if (i < 2228224) {
    src = conv_w; dst = convb; off = i - 2097152;
  } else {
    src = pw_w; dst = pwb; off = i - 2228224;
  }
  float4 a = ((const float4*)src)[off * 2];
  float4 b = ((const float4*)src)[off * 2 + 1];
  sh8 o;
  o[0] = f2bf(a.x); o[1] = f2bf(a.y); o[2] = f2bf(a.z); o[3] = f2bf(a.w);
  o[4] = f2bf(b.x); o[5] = f2bf(b.y); o[6] = f2bf(b.z); o[7] = f2bf(b.w);
  ((sh8*)dst)[off] = o;
}

// -------- one transpose kernel: qkv_w (z=0..2), out_w (z=3), tok_w (z=4) ---
__global__ __launch_bounds__(256) void transpose3(
    const float* __restrict__ qkv_w, const float* __restrict__ out_w,
    const float* __restrict__ tok_w, short* __restrict__ wbig,
    short* __restrict__ wcatT) {
  __shared__ float tile[32][33];
  int z = blockIdx.z;
  const float* src;
  short* dst;
  int N, ldd, coff, nb;
  if (z < 3) {
    src = qkv_w; dst = wbig; N = 3072; ldd = 1024; coff = 0;
    nb = z * 1024 + blockIdx.x * 32;
  } else if (z == 3) {
    src = out_w; dst = wcatT; N = 1024; ldd = 2048; coff = 0;
    nb = blockIdx.x * 32;
  } else {
    src = tok_w; dst = wcatT; N = 1024; ldd = 2048; coff = 1024;
    nb = blockIdx.x * 32;
  }
  int kb = blockIdx.y * 32;
  int tx = threadIdx.x, ty = threadIdx.y;
#pragma unroll
  for (int j = 0; j < 32; j += 8)
    tile[ty + j][tx] = src[(size_t)(kb + ty + j) * N + nb + tx];
  __syncthreads();
#pragma unroll
  for (int j = 0; j < 32; j += 8)
    dst[(size_t)(nb + ty + j) * ldd + coff + kb + tx] = f2bf(tile[tx][ty + j]);
}

// --------------------------- misc bias / dw prep ---------------------------
__global__ __launch_bounds__(256) void prep_misc(
    const float* __restrict__ pw_w, const float* __restrict__ conv_b,
    const float* __restrict__ pw_b, const float* __restrict__ qkv_b,
    const float* __restrict__ out_b, const float* __restrict__ tok_b,
    const float* __restrict__ dw_w, const float* __restrict__ dw_b,
    float* __restrict__ bias4, float* __restrict__ bcat,
    float* __restrict__ dw0, float* __restrict__ dw1,
    float* __restrict__ dw2, float* __restrict__ dwb) {
  int o = blockIdx.x;
  if (o < 1024) {
    float part = 0.f;
    for (int i = threadIdx.x; i < 1024; i += 256)
      part += pw_w[(size_t)o * 1024 + i] * conv_b[i];
#pragma unroll
    for (int off = 32; off >= 1; off >>= 1) part += __shfl_down(part, off);
    __shared__ float red[4];
    int wid = threadIdx.x >> 6, lane = threadIdx.x & 63;
    if (lane == 0) red[wid] = part;
    __syncthreads();
    if (threadIdx.x == 0) {
      float s = red[0] + red[1] + red[2] + red[3];
      bias4[3072 + o] = s + pw_b[o];
      bcat[o] = out_b[o] + tok_b[o];
      dw0[o] = dw_w[o * 3 + 0];
      dw1[o] = dw_w[o * 3 + 1];
      dw2[o] = dw_w[o * 3 + 2];
      dwb[o] = dw_b[o];
    }
  }
  if (threadIdx.x == 0) bias4[o] = qkv_b[o];
}

// --------------------- bf16 GEMM, 128x128 (prep only) ----------------------
template <int OUT_BF16>
__global__ __launch_bounds__(256, 2) void gemm128(
    const short* __restrict__ A, const short* __restrict__ Bt,
    void* __restrict__ Cp, const float* __restrict__ bias, int K, int ldc) {
  __shared__ short As[128 * 32];
  __shared__ short Bs[128 * 32];
  const int wid = threadIdx.x >> 6, lane = threadIdx.x & 63;
  const int bm = blockIdx.y, bn = blockIdx.x;
  const int wr = wid >> 1, wc = wid & 1;
  const size_t abase = (size_t)bm * 128 * K;
  const size_t bbase = (size_t)bn * 128 * K;
  const int r16 = lane & 15, ko = (lane >> 4) * 8;

  f4 acc[4][4] = {};

  for (int k0 = 0; k0 < K; k0 += 32) {
    __syncthreads();
#pragma unroll
    for (int c = 0; c < 2; ++c) {
      int ch = c * 256 + wid * 64 + lane;
      int row = ch >> 2, kc = (ch & 3) * 8;
      g2l16(A + abase + (size_t)row * K + k0 + kc, &As[ch * 8]);
      g2l16(Bt + bbase + (size_t)row * K + k0 + kc, &Bs[ch * 8]);
    }
    __syncthreads();
    sh8 af[4], bf[4];
#pragma unroll
    for (int i = 0; i < 4; ++i)
      af[i] = *(const sh8*)&As[(wr * 64 + i * 16 + r16) * 32 + ko];
#pragma unroll
    for (int j = 0; j < 4; ++j)
      bf[j] = *(const sh8*)&Bs[(wc * 64 + j * 16 + r16) * 32 + ko];
#pragma unroll
    for (int i = 0; i < 4; ++i)
#pragma unroll
      for (int j = 0; j < 4; ++j)
        acc[i][j] = __builtin_amdgcn_mfma_f32_16x16x32_bf16(af[i], bf[j],
                                                            acc[i][j], 0, 0, 0);
  }

  const int crow = wr * 64 + (lane >> 4) * 4;
  const int ccol = wc * 64 + r16;
#pragma unroll
  for (int i = 0; i < 4; ++i) {
#pragma unroll
    for (int j = 0; j < 4; ++j) {
      int col = bn * 128 + ccol + j * 16;
      float bv = bias ? bias[col] : 0.f;
#pragma unroll
      for (int r = 0; r < 4; ++r) {
        int row = bm * 128 + crow + i * 16 + r;
        float v = acc[i][j][r] + bv;
        if (OUT_BF16)
          ((short*)Cp)[(size_t)row * ldc + col] = f2bf(v);
        else
          ((float*)Cp)[(size_t)row * ldc + col] = v;
      }
    }
  }
}

// ------- bf16 GEMM, 256x256, register-dbuf fragments + depth-3 DMA ---------
template <int OUT_BF16>
__global__ __launch_bounds__(512, 2) void gemm256(
    const short* __restrict__ A, const short* __restrict__ Bt,
    void* __restrict__ Cp, const float* __restrict__ bias,
    int K, int ldc, int nbn) {
  __shared__ short lds[65536];  // 128 KiB
  const int tid = threadIdx.x;
  const int lane = tid & 63, wid = tid >> 6;
  const int wr = wid >> 2, wc = wid & 3;
  const int r16 = lane & 15;
  const int kidx = ((lane >> 4) ^ ((r16 >> 1) & 3)) << 3;

  const int cpx = gridDim.x >> 3;
  const int swz = (blockIdx.x & 7) * cpx + (blockIdx.x >> 3);
  const int bm = swz / nbn, bn = swz % nbn;

  const short* Ag = A + (size_t)bm * 256 * K;
  const short* Bg = Bt + (size_t)bn * 256 * K;

  int goff0, goff1, loff0, loff1;
  {
    int s0 = tid, row0 = s0 >> 2;
    int kc0 = (s0 & 3) ^ ((row0 >> 1) & 3);
    goff0 = row0 * K + kc0 * 8;
    loff0 = s0 * 8;
    int s1 = 512 + tid, row1 = s1 >> 2;
    int kc1 = (s1 & 3) ^ ((row1 >> 1) & 3);
    goff1 = row1 * K + kc1 * 8;
    loff1 = s1 * 8;
  }

  f4 acc[8][4] = {};
  const int NT = K >> 5;

#define STAGE_FULL(KT, B)                                   \
  do {                                                      \
    short* lb = &lds[(B) * 16384];                          \
    const short* ga = Ag + (KT) * 32;                       \
    const short* gb = Bg + (KT) * 32;                       \
    g2l16(ga + goff0, lb + loff0);                          \
    g2l16(gb + goff0, lb + 8192 + loff0);                   \
    g2l16(ga + goff1, lb + loff1);                          \
    g2l16(gb + goff1, lb + 8192 + loff1);                   \
  } while (0)

#define LOADFRAG(AF, BF, BUFIDX)                                          \
  do {                                                                    \
    const short* Ab_ = &lds[(BUFIDX) * 16384];                            \
    const short* Bb_ = Ab_ + 8192;                                        \
    _Pragma("unroll")                                                     \
    for (int i = 0; i < 8; ++i)                                           \
      AF[i] = *(const sh8*)&Ab_[(wr * 128 + i * 16 + r16) * 32 + kidx];   \
    _Pragma("unroll")                                                     \
    for (int j = 0; j < 4; ++j)                                           \
      BF[j] = *(const sh8*)&Bb_[(wc * 64 + j * 16 + r16) * 32 + kidx];    \
  } while (0)

#define MFMA_ALL(AF, BF)                                                  \
  do {                                                                    \
    _Pragma("unroll")                                                     \
    for (int i = 0; i < 8; ++i)                                           \
      _Pragma("unroll")                                                   \
      for (int j = 0; j < 4; ++j)                                         \
        acc[i][j] = __builtin_amdgcn_mfma_f32_16x16x32_bf16(              \
            AF[i], BF[j], acc[i][j], 0, 0, 0);                            \
  } while (0)

  STAGE_FULL(0, 0);
  STAGE_FULL(1, 1);
  STAGE_FULL(2, 2);
  asm volatile("s_waitcnt vmcnt(4)" ::: "memory");
  __builtin_amdgcn_sched_barrier(0);
  __builtin_amdgcn_s_barrier();
  __builtin_amdgcn_sched_barrier(0);

  sh8 afA[8], bfA[4], afB[8], bfB[4];
  LOADFRAG(afA, bfA, 0);

  for (int t = 0; t < NT; t += 2) {
    LOADFRAG(afB, bfB, (t + 1) & 3);
    {
      const int kt = (t + 3 < NT) ? t + 3 : 0;
      STAGE_FULL(kt, (t + 3) & 3);
    }
    __builtin_amdgcn_s_setprio(1);
    MFMA_ALL(afA, bfA);
    __builtin_amdgcn_s_setprio(0);
    __builtin_amdgcn_sched_barrier(0);
    asm volatile("s_waitcnt vmcnt(4)" ::: "memory");
    __builtin_amdgcn_sched_barrier(0);
    __builtin_amdgcn_s_barrier();
    __builtin_amdgcn_sched_barrier(0);

    LOADFRAG(afA, bfA, (t + 2) & 3);
    {
      const int kt = (t + 4 < NT) ? t + 4 : 0;
      STAGE_FULL(kt, (t + 4) & 3);
    }
    __builtin_amdgcn_s_setprio(1);
    MFMA_ALL(afB, bfB);
    __builtin_amdgcn_s_setprio(0);
    __builtin_amdgcn_sched_barrier(0);
    asm volatile("s_waitcnt vmcnt(4)" ::: "memory");
    __builtin_amdgcn_sched_barrier(0);
    __builtin_amdgcn_s_barrier();
    __builtin_amdgcn_sched_barrier(0);
  }
#undef STAGE_FULL
#undef LOADFRAG
#undef MFMA_ALL

  const int crow0 = bm * 256 + wr * 128 + (lane >> 4) * 4;
  const int ccol0 = bn * 256 + wc * 64 + r16;
  float bv[4];
#pragma unroll
  for (int j = 0; j < 4; ++j) bv[j] = bias ? bias[ccol0 + j * 16] : 0.f;
#pragma unroll
  for (int i = 0; i < 8; ++i) {
#pragma unroll
    for (int r = 0; r < 4; ++r) {
      size_t rowoff = (size_t)(crow0 + i * 16 + r) * ldc + ccol0;
#pragma unroll
      for (int j = 0; j < 4; ++j) {
        float v = acc[i][j][r] + bv[j];
        if (OUT_BF16)
          ((short*)Cp)[rowoff + j * 16] = f2bf(v);
        else
          ((float*)Cp)[rowoff + j * 16] = v;
      }
    }
  }
}

// ---------- fused epilogue: MFMA attention (S^T trick) + depthwise ---------
// One block = 4 tokens, 4 waves; wave wid owns token t0+wid.
// sq: per token 16 heads x 208 shorts (pad; q@0, k@64, v@128 within head).
// S^T = mfma(A=k, B=q): lane holds S[h=lane&15][g=(lane>>4)*4+r].
// Softmax over g: per-lane max/sum over r + shfl_xor(16,32).
// P -> A-layout of 16x16x32 via 8 shfl (K padded to 32, lanes>=32 zero).
// PV: B = vT[d][g] (pad 24, b128 reads), 4 MFMA over d-chunks.
__global__ __launch_bounds__(256) void epilogue(
    const short* __restrict__ qkvx, const float* __restrict__ pos_bias,
    const float* __restrict__ dw0, const float* __restrict__ dw1,
    const float* __restrict__ dw2, const float* __restrict__ dwb,
    short* __restrict__ xcat) {
  __shared__ short sq[4 * 3328];      // 4 tok x 16 heads x 208
  __shared__ short slice[6 * 1024];   // rows t0-1..t0+4 x cols 3072-4095
  __shared__ short vT[4 * 1536];      // per tok: [64 d][24 pad] (g in 0..15)
  int t0 = blockIdx.x * 4;
#pragma unroll
  for (int it = 0; it < 6; ++it) {
    int g = it * 256 + threadIdx.x;   // 1536 chunks = 4 tok x 384
    int tok = (g * 683) >> 18;        // g / 384 for g < 1536
    int c = g - tok * 384;
    int hd = c / 24, wi = c - hd * 24;  // 24 chunks of 8 per head
    *(sh8*)(sq + tok * 3328 + hd * 208 + wi * 8) =
        *(const sh8*)(qkvx + (size_t)(t0 + tok) * 4096 + c * 8);
  }
#pragma unroll
  for (int s = 0; s < 3; ++s) {
    int g = s * 256 + threadIdx.x;    // 768 chunks = 6 rows x 128
    int r = g >> 7, off = g & 127;
    int gr = t0 - 1 + r;
    sh8 v = {};
    if (gr >= 0 && gr < 16384)
      v = *(const sh8*)(qkvx + (size_t)gr * 4096 + 3072 + off * 8);
    ((sh8*)slice)[g] = v;
  }
  __syncthreads();

  int wid = threadIdx.x >> 6, lane = threadIdx.x & 63;
  int t = t0 + wid, n = t & 4095;
  int lg = lane & 15, lk = lane >> 4;
  const short* tb = sq + wid * 3328;
  short* vt = vT + wid * 1536;

  // build vT for own token: lane handles column d = lane
  {
    int d = lane;
    short tmp[16];
#pragma unroll
    for (int g = 0; g < 16; ++g) tmp[g] = tb[g * 208 + 128 + d];
#pragma unroll
    for (int g0 = 0; g0 < 16; g0 += 4)
      *(sh4*)(vt + d * 24 + g0) = *(const sh4*)&tmp[g0];
  }

  // S^T = K @ Q^T  (A=k rows g, B=q cols h, K-dim = d in 2 steps of 32)
  f4 s = {};
  {
    sh8 kf0 = *(const sh8*)(tb + lg * 208 + 64 + lk * 8);
    sh8 qf0 = *(const sh8*)(tb + lg * 208 + lk * 8);
    s = __builtin_amdgcn_mfma_f32_16x16x32_bf16(kf0, qf0, s, 0, 0, 0);
    sh8 kf1 = *(const sh8*)(tb + lg * 208 + 96 + lk * 8);
    sh8 qf1 = *(const sh8*)(tb + lg * 208 + 32 + lk * 8);
    s = __builtin_amdgcn_mfma_f32_16x16x32_bf16(kf1, qf1, s, 0, 0, 0);
  }

  // scores + bias; softmax over g (regs r + lanes ^16 ^32 share h=lg)
  f4 pbv = *(const f4*)(pos_bias + (size_t)n * 256 + lg * 16 + lk * 4);
  float e[4];
  float m = -1e30f;
#pragma unroll
  for (int r = 0; r < 4; ++r) {
    e[r] = s[r] * 0.125f + pbv[r];
    m = fmaxf(m, e[r]);
  }
  m = fmaxf(m, __shfl_xor(m, 16));
  m = fmaxf(m, __shfl_xor(m, 32));
  float sum = 0.f;
#pragma unroll
  for (int r = 0; r < 4; ++r) {
    e[r] = __expf(e[r] - m);
    sum += e[r];
  }
  sum += __shfl_xor(sum, 16);
  sum += __shfl_xor(sum, 32);
  float inv = 1.0f / sum;
#pragma unroll
  for (int r = 0; r < 4; ++r) e[r] *= inv;

  // redistribute P to 16x16x32 A-layout: lane (h=lg, k=g=lk*8+j), lanes>=32 zero
  sh8 ap;
#pragma unroll
  for (int j = 0; j < 8; ++j) {
    float pv_ = __shfl(e[j & 3], (((lk & 1) * 2 + (j >> 2)) * 16) + lg);
    ap[j] = (lk < 2) ? f2bf(pv_) : (short)0;
  }

  // PV: per d-chunk c, B[k=g][n=d_local=lg] = vT[c*16+lg][ (lk&1)*8 + j ]
  f4 pv[4] = {};
#pragma unroll
  for (int c = 0; c < 4; ++c) {
    sh8 bf = *(const sh8*)(vt + (c * 16 + lg) * 24 + (lk & 1) * 8);
    pv[c] = __builtin_amdgcn_mfma_f32_16x16x32_bf16(ap, bf, pv[c], 0, 0, 0);
  }

  // O[h=(lk*4+r)][d=c*16+lg] -> xcat[t][h*64+d]
  short* dst = xcat + (size_t)t * 2048;
#pragma unroll
  for (int c = 0; c < 4; ++c)
#pragma unroll
    for (int r = 0; r < 4; ++r)
      dst[(lk * 4 + r) * 64 + c * 16 + lg] = f2bf(pv[c][r]);

  // ---- depthwise conv from LDS slice: 2 outputs of 8 channels per thread --
#pragma unroll
  for (int it = 0; it < 2; ++it) {
    int w = it * 256 + threadIdx.x;   // 512 = 4 tok x 64 col-chunks
    int tok = w >> 7, co = (w & 127) * 8;
    int tt = t0 + tok, nn = tt & 4095;
    const short* lo8 = slice + tok * 1024 + co;
    const short* mi8 = lo8 + 1024;
    const short* hi8 = lo8 + 2048;
    sh8 lo = (nn > 0) ? *(const sh8*)lo8 : sh8{};
    sh8 mi = *(const sh8*)mi8;
    sh8 hi = (nn < 4095) ? *(const sh8*)hi8 : sh8{};
    sh8 out;
#pragma unroll
    for (int j = 0; j < 8; ++j) {
      float v = dw0[co + j] * bf2f(lo[j]) + dw1[co + j] * bf2f(mi[j]) +
                dw2[co + j] * bf2f(hi[j]) + dwb[co + j];
      out[j] = f2bf(v);
    }
    *(sh8*)(xcat + (size_t)tt * 2048 + 1024 + co) = out;
  }
}

// ---------------------------------------------------------------------------
extern "C" void kernel_launch(void* const* d_in, const int* in_sizes, int n_in,
                              void* d_out, int out_size, void* d_ws,
                              size_t ws_size, hipStream_t stream) {
  const float* x      = (const float*)d_in[0];
  const float* qkv_w  = (const float*)d_in[1];
  const float* qkv_b  = (const float*)d_in[2];
  const float* out_w  = (const float*)d_in[3];
  const float* out_b  = (const float*)d_in[4];
  const float* pos_b  = (const float*)d_in[5];
  const float* conv_w = (const float*)d_in[6];
  const float* conv_b = (const float*)d_in[7];
  const float* pw_w   = (const float*)d_in[8];
  const float* pw_b   = (const float*)d_in[9];
  const float* dw_w   = (const float*)d_in[10];
  const float* dw_b   = (const float*)d_in[11];
  const float* tok_w  = (const float*)d_in[12];
  const float* tok_b  = (const float*)d_in[13];

  const int M = 16384;
  char* ws = (char*)d_ws;
  size_t off = 0;
  auto alloc = [&](size_t bytes) -> void* {
    void* p = ws + off;
    off += (bytes + 255) & ~(size_t)255;
    return p;
  };
  short* xb    = (short*)alloc((size_t)M * 1024 * 2);
  short* wbig  = (short*)alloc((size_t)4096 * 1024 * 2);  // [qkv_w^T | W2^T]
  short* wcatT = (short*)alloc((size_t)1024 * 2048 * 2);
  short* convb = (short*)alloc((size_t)1024 * 1024 * 2);
  short* pwb   = (short*)alloc((size_t)1024 * 1024 * 2);
  short* qkvx  = (short*)alloc((size_t)M * 4096 * 2);
  short* xcat  = (short*)alloc((size_t)M * 2048 * 2);
  float* bias4 = (float*)alloc(4096 * 4);
  float* bcat  = (float*)alloc(1024 * 4);
  float* dw0   = (float*)alloc(1024 * 4);
  float* dw1   = (float*)alloc(1024 * 4);
  float* dw2   = (float*)alloc(1024 * 4);
  float* dwb   = (float*)alloc(1024 * 4);
  (void)ws_size; (void)in_sizes; (void)n_in; (void)out_size;

  // weight prep (consolidated launches)
  cvt3<<<9216, 256, 0, stream>>>(x, conv_w, pw_w, xb, convb, pwb);
  transpose3<<<dim3(32, 32, 5), dim3(32, 8), 0, stream>>>(qkv_w, out_w, tok_w,
                                                          wbig, wcatT);
  prep_misc<<<3072, 256, 0, stream>>>(pw_w, conv_b, pw_b, qkv_b, out_b, tok_b,
                                      dw_w, dw_b, bias4, bcat, dw0, dw1, dw2, dwb);
  // W2^T[o][p] = sum_i pw_w[o][i] * conv_w[p][i] -> rows 3072+ of wbig
  gemm128<1><<<dim3(8, 8), 256, 0, stream>>>(pwb, convb, wbig + (size_t)3072 * 1024,
                                             nullptr, 1024, 1024);

  // fused qkv+conv GEMM: [M,1024] @ [4096,1024]^T -> [M,4096]
  gemm256<1><<<1024, 512, 0, stream>>>(xb, wbig, qkvx, bias4, 1024, 4096, 16);

  // fused MFMA attention + depthwise epilogue
  epilogue<<<4096, 256, 0, stream>>>(qkvx, pos_b, dw0, dw1, dw2, dwb, xcat);

  // out = xcat @ [out_w; tok_w] + (out_b + tok_b)
  gemm256<0><<<256, 512, 0, stream>>>(xcat, wcatT, d_out, bcat, 2048, 1024, 4);
}

// Round 19
// 303.921 us; speedup vs baseline: 1.3317x; 1.0104x over previous
//
#include <hip/hip_runtime.h>
#include <hip/hip_bf16.h>

// ---------------------------------------------------------------------------
// REMSA fused block on MI355X.
//   - gemm256: round-9 register-dbuf fragments + depth-3 DMA (141 us fused)
//   - epilogue: MFMA-based per-token attention (S^T trick) + direct-read dwconv
//   - prep: consolidated cvt3 / transpose3
//
//   xb    = bf16(x)                                   [M,1024]
//   W2    = conv_w @ pw_w^T (prefused), b2 fused      [1024,1024]
//   qkvx  = xb @ [qkv_w | W2] + [qkv_b | b2]          [M,4096]  (gemm256)
//   attn / depthwise3 epilogue (one kernel)           -> xcat [M,2048]
//   out   = xcat @ [out_w; tok_w] + (out_b+tok_b)     [M,1024]  (gemm256 K=2048)
// ---------------------------------------------------------------------------

typedef __attribute__((ext_vector_type(8))) short sh8;
typedef __attribute__((ext_vector_type(4))) short sh4;
typedef __attribute__((ext_vector_type(4))) float f4;

__device__ __forceinline__ float bf2f(short s) {
  unsigned u = ((unsigned)(unsigned short)s) << 16;
  return __builtin_bit_cast(float, u);
}
__device__ __forceinline__ short f2bf(float f) {
  return __builtin_bit_cast(short, __float2bfloat16(f));
}
__device__ __forceinline__ void g2l16(const void* g, void* l) {
  __builtin_amdgcn_global_load_lds(
      (const __attribute__((address_space(1))) unsigned int*)g,
      (__attribute__((address_space(3))) unsigned int*)l, 16, 0, 0);
}

// ---------------- f32 -> bf16 convert (x, conv_w, pw_w in one) -------------
__global__ __launch_bounds__(256) void cvt3(
    const float* __restrict__ x, const float* __restrict__ conv_w,
    const float* __restrict__ pw_w, short* __restrict__ xb,
    short* __restrict__ convb, short* __restrict__ pwb) {
  int i = blockIdx.x * 256 + threadIdx.x;  // 9216*256 = 2359296 chunks
  const float* src;
  short* dst;
  int off;
  if (i < 2097152) {
    src = x; dst = xb; off = i;
  } else if (i < 2228224) {
    src = conv_w; dst = convb; off = i - 2097152;
  } else {
    src = pw_w; dst = pwb; off = i - 2228224;
  }
  float4 a = ((const float4*)src)[off * 2];
  float4 b = ((const float4*)src)[off * 2 + 1];
  sh8 o;
  o[0] = f2bf(a.x); o[1] = f2bf(a.y); o[2] = f2bf(a.z); o[3] = f2bf(a.w);
  o[4] = f2bf(b.x); o[5] = f2bf(b.y); o[6] = f2bf(b.z); o[7] = f2bf(b.w);
  ((sh8*)dst)[off] = o;
}

// -------- one transpose kernel: qkv_w (z=0..2), out_w (z=3), tok_w (z=4) ---
__global__ __launch_bounds__(256) void transpose3(
    const float* __restrict__ qkv_w, const float* __restrict__ out_w,
    const float* __restrict__ tok_w, short* __restrict__ wbig,
    short* __restrict__ wcatT) {
  __shared__ float tile[32][33];
  int z = blockIdx.z;
  const float* src;
  short* dst;
  int N, ldd, coff, nb;
  if (z < 3) {
    src = qkv_w; dst = wbig; N = 3072; ldd = 1024; coff = 0;
    nb = z * 1024 + blockIdx.x * 32;
  } else if (z == 3) {
    src = out_w; dst = wcatT; N = 1024; ldd = 2048; coff = 0;
    nb = blockIdx.x * 32;
  } else {
    src = tok_w; dst = wcatT; N = 1024; ldd = 2048; coff = 1024;
    nb = blockIdx.x * 32;
  }
  int kb = blockIdx.y * 32;
  int tx = threadIdx.x, ty = threadIdx.y;
#pragma unroll
  for (int j = 0; j < 32; j += 8)
    tile[ty + j][tx] = src[(size_t)(kb + ty + j) * N + nb + tx];
  __syncthreads();
#pragma unroll
  for (int j = 0; j < 32; j += 8)
    dst[(size_t)(nb + ty + j) * ldd + coff + kb + tx] = f2bf(tile[tx][ty + j]);
}

// --------------------------- misc bias / dw prep ---------------------------
__global__ __launch_bounds__(256) void prep_misc(
    const float* __restrict__ pw_w, const float* __restrict__ conv_b,
    const float* __restrict__ pw_b, const float* __restrict__ qkv_b,
    const float* __restrict__ out_b, const float* __restrict__ tok_b,
    const float* __restrict__ dw_w, const float* __restrict__ dw_b,
    float* __restrict__ bias4, float* __restrict__ bcat,
    float* __restrict__ dw0, float* __restrict__ dw1,
    float* __restrict__ dw2, float* __restrict__ dwb) {
  int o = blockIdx.x;
  if (o < 1024) {
    float part = 0.f;
    for (int i = threadIdx.x; i < 1024; i += 256)
      part += pw_w[(size_t)o * 1024 + i] * conv_b[i];
#pragma unroll
    for (int off = 32; off >= 1; off >>= 1) part += __shfl_down(part, off);
    __shared__ float red[4];
    int wid = threadIdx.x >> 6, lane = threadIdx.x & 63;
    if (lane == 0) red[wid] = part;
    __syncthreads();
    if (threadIdx.x == 0) {
      float s = red[0] + red[1] + red[2] + red[3];
      bias4[3072 + o] = s + pw_b[o];
      bcat[o] = out_b[o] + tok_b[o];
      dw0[o] = dw_w[o * 3 + 0];
      dw1[o] = dw_w[o * 3 + 1];
      dw2[o] = dw_w[o * 3 + 2];
      dwb[o] = dw_b[o];
    }
  }
  if (threadIdx.x == 0) bias4[o] = qkv_b[o];
}

// --------------------- bf16 GEMM, 128x128 (prep only) ----------------------
template <int OUT_BF16>
__global__ __launch_bounds__(256, 2) void gemm128(
    const short* __restrict__ A, const short* __restrict__ Bt,
    void* __restrict__ Cp, const float* __restrict__ bias, int K, int ldc) {
  __shared__ short As[128 * 32];
  __shared__ short Bs[128 * 32];
  const int wid = threadIdx.x >> 6, lane = threadIdx.x & 63;
  const int bm = blockIdx.y, bn = blockIdx.x;
  const int wr = wid >> 1, wc = wid & 1;
  const size_t abase = (size_t)bm * 128 * K;
  const size_t bbase = (size_t)bn * 128 * K;
  const int r16 = lane & 15, ko = (lane >> 4) * 8;

  f4 acc[4][4] = {};

  for (int k0 = 0; k0 < K; k0 += 32) {
    __syncthreads();
#pragma unroll
    for (int c = 0; c < 2; ++c) {
      int ch = c * 256 + wid * 64 + lane;
      int row = ch >> 2, kc = (ch & 3) * 8;
      g2l16(A + abase + (size_t)row * K + k0 + kc, &As[ch * 8]);
      g2l16(Bt + bbase + (size_t)row * K + k0 + kc, &Bs[ch * 8]);
    }
    __syncthreads();
    sh8 af[4], bf[4];
#pragma unroll
    for (int i = 0; i < 4; ++i)
      af[i] = *(const sh8*)&As[(wr * 64 + i * 16 + r16) * 32 + ko];
#pragma unroll
    for (int j = 0; j < 4; ++j)
      bf[j] = *(const sh8*)&Bs[(wc * 64 + j * 16 + r16) * 32 + ko];
#pragma unroll
    for (int i = 0; i < 4; ++i)
#pragma unroll
      for (int j = 0; j < 4; ++j)
        acc[i][j] = __builtin_amdgcn_mfma_f32_16x16x32_bf16(af[i], bf[j],
                                                            acc[i][j], 0, 0, 0);
  }

  const int crow = wr * 64 + (lane >> 4) * 4;
  const int ccol = wc * 64 + r16;
#pragma unroll
  for (int i = 0; i < 4; ++i) {
#pragma unroll
    for (int j = 0; j < 4; ++j) {
      int col = bn * 128 + ccol + j * 16;
      float bv = bias ? bias[col] : 0.f;
#pragma unroll
      for (int r = 0; r < 4; ++r) {
        int row = bm * 128 + crow + i * 16 + r;
        float v = acc[i][j][r] + bv;
        if (OUT_BF16)
          ((short*)Cp)[(size_t)row * ldc + col] = f2bf(v);
        else
          ((float*)Cp)[(size_t)row * ldc + col] = v;
      }
    }
  }
}

// ------- bf16 GEMM, 256x256, register-dbuf fragments + depth-3 DMA ---------
template <int OUT_BF16>
__global__ __launch_bounds__(512, 2) void gemm256(
    const short* __restrict__ A, const short* __restrict__ Bt,
    void* __restrict__ Cp, const float* __restrict__ bias,
    int K, int ldc, int nbn) {
  __shared__ short lds[65536];  // 128 KiB
  const int tid = threadIdx.x;
  const int lane = tid & 63, wid = tid >> 6;
  const int wr = wid >> 2, wc = wid & 3;
  const int r16 = lane & 15;
  const int kidx = ((lane >> 4) ^ ((r16 >> 1) & 3)) << 3;

  const int cpx = gridDim.x >> 3;
  const int swz = (blockIdx.x & 7) * cpx + (blockIdx.x >> 3);
  const int bm = swz / nbn, bn = swz % nbn;

  const short* Ag = A + (size_t)bm * 256 * K;
  const short* Bg = Bt + (size_t)bn * 256 * K;

  int goff0, goff1, loff0, loff1;
  {
    int s0 = tid, row0 = s0 >> 2;
    int kc0 = (s0 & 3) ^ ((row0 >> 1) & 3);
    goff0 = row0 * K + kc0 * 8;
    loff0 = s0 * 8;
    int s1 = 512 + tid, row1 = s1 >> 2;
    int kc1 = (s1 & 3) ^ ((row1 >> 1) & 3);
    goff1 = row1 * K + kc1 * 8;
    loff1 = s1 * 8;
  }

  f4 acc[8][4] = {};
  const int NT = K >> 5;

#define STAGE_FULL(KT, B)                                   \
  do {                                                      \
    short* lb = &lds[(B) * 16384];                          \
    const short* ga = Ag + (KT) * 32;                       \
    const short* gb = Bg + (KT) * 32;                       \
    g2l16(ga + goff0, lb + loff0);                          \
    g2l16(gb + goff0, lb + 8192 + loff0);                   \
    g2l16(ga + goff1, lb + loff1);                          \
    g2l16(gb + goff1, lb + 8192 + loff1);                   \
  } while (0)

#define LOADFRAG(AF, BF, BUFIDX)                                          \
  do {                                                                    \
    const short* Ab_ = &lds[(BUFIDX) * 16384];                            \
    const short* Bb_ = Ab_ + 8192;                                        \
    _Pragma("unroll")                                                     \
    for (int i = 0; i < 8; ++i)                                           \
      AF[i] = *(const sh8*)&Ab_[(wr * 128 + i * 16 + r16) * 32 + kidx];   \
    _Pragma("unroll")                                                     \
    for (int j = 0; j < 4; ++j)                                           \
      BF[j] = *(const sh8*)&Bb_[(wc * 64 + j * 16 + r16) * 32 + kidx];    \
  } while (0)

#define MFMA_ALL(AF, BF)                                                  \
  do {                                                                    \
    _Pragma("unroll")                                                     \
    for (int i = 0; i < 8; ++i)                                           \
      _Pragma("unroll")                                                   \
      for (int j = 0; j < 4; ++j)                                         \
        acc[i][j] = __builtin_amdgcn_mfma_f32_16x16x32_bf16(              \
            AF[i], BF[j], acc[i][j], 0, 0, 0);                            \
  } while (0)

  STAGE_FULL(0, 0);
  STAGE_FULL(1, 1);
  STAGE_FULL(2, 2);
  asm volatile("s_waitcnt vmcnt(4)" ::: "memory");
  __builtin_amdgcn_sched_barrier(0);
  __builtin_amdgcn_s_barrier();
  __builtin_amdgcn_sched_barrier(0);

  sh8 afA[8], bfA[4], afB[8], bfB[4];
  LOADFRAG(afA, bfA, 0);

  for (int t = 0; t < NT; t += 2) {
    LOADFRAG(afB, bfB, (t + 1) & 3);
    {
      const int kt = (t + 3 < NT) ? t + 3 : 0;
      STAGE_FULL(kt, (t + 3) & 3);
    }
    __builtin_amdgcn_s_setprio(1);
    MFMA_ALL(afA, bfA);
    __builtin_amdgcn_s_setprio(0);
    __builtin_amdgcn_sched_barrier(0);
    asm volatile("s_waitcnt vmcnt(4)" ::: "memory");
    __builtin_amdgcn_sched_barrier(0);
    __builtin_amdgcn_s_barrier();
    __builtin_amdgcn_sched_barrier(0);

    LOADFRAG(afA, bfA, (t + 2) & 3);
    {
      const int kt = (t + 4 < NT) ? t + 4 : 0;
      STAGE_FULL(kt, (t + 4) & 3);
    }
    __builtin_amdgcn_s_setprio(1);
    MFMA_ALL(afB, bfB);
    __builtin_amdgcn_s_setprio(0);
    __builtin_amdgcn_sched_barrier(0);
    asm volatile("s_waitcnt vmcnt(4)" ::: "memory");
    __builtin_amdgcn_sched_barrier(0);
    __builtin_amdgcn_s_barrier();
    __builtin_amdgcn_sched_barrier(0);
  }
#undef STAGE_FULL
#undef LOADFRAG
#undef MFMA_ALL

  const int crow0 = bm * 256 + wr * 128 + (lane >> 4) * 4;
  const int ccol0 = bn * 256 + wc * 64 + r16;
  float bv[4];
#pragma unroll
  for (int j = 0; j < 4; ++j) bv[j] = bias ? bias[ccol0 + j * 16] : 0.f;
#pragma unroll
  for (int i = 0; i < 8; ++i) {
#pragma unroll
    for (int r = 0; r < 4; ++r) {
      size_t rowoff = (size_t)(crow0 + i * 16 + r) * ldc + ccol0;
#pragma unroll
      for (int j = 0; j < 4; ++j) {
        float v = acc[i][j][r] + bv[j];
        if (OUT_BF16)
          ((short*)Cp)[rowoff + j * 16] = f2bf(v);
        else
          ((float*)Cp)[rowoff + j * 16] = v;
      }
    }
  }
}

// ---------- fused epilogue: MFMA attention (S^T trick) + dwconv ------------
// One block = 4 tokens, 4 waves; wave wid owns token t0+wid.
// Attention: MFMA S^T trick (round-18 verified).  Depthwise: direct global
// reads (rounds 8-13 verified form) — neighbor rows are L2-resident, no
// LDS staging needed (Common-mistake #7).
__global__ __launch_bounds__(256) void epilogue(
    const short* __restrict__ qkvx, const float* __restrict__ pos_bias,
    const float* __restrict__ dw0, const float* __restrict__ dw1,
    const float* __restrict__ dw2, const float* __restrict__ dwb,
    short* __restrict__ xcat) {
  __shared__ short sq[4 * 3328];      // 4 tok x 16 heads x 208
  __shared__ short vT[4 * 1536];      // per tok: [64 d][24 pad] (g in 0..15)
  int t0 = blockIdx.x * 4;
#pragma unroll
  for (int it = 0; it < 6; ++it) {
    int g = it * 256 + threadIdx.x;   // 1536 chunks = 4 tok x 384
    int tok = (g * 683) >> 18;        // g / 384 for g < 1536
    int c = g - tok * 384;
    int hd = c / 24, wi = c - hd * 24;  // 24 chunks of 8 per head
    *(sh8*)(sq + tok * 3328 + hd * 208 + wi * 8) =
        *(const sh8*)(qkvx + (size_t)(t0 + tok) * 4096 + c * 8);
  }
  __syncthreads();

  int wid = threadIdx.x >> 6, lane = threadIdx.x & 63;
  int t = t0 + wid, n = t & 4095;
  int lg = lane & 15, lk = lane >> 4;
  const short* tb = sq + wid * 3328;
  short* vt = vT + wid * 1536;

  // build vT for own token: lane handles column d = lane
  {
    int d = lane;
    short tmp[16];
#pragma unroll
    for (int g = 0; g < 16; ++g) tmp[g] = tb[g * 208 + 128 + d];
#pragma unroll
    for (int g0 = 0; g0 < 16; g0 += 4)
      *(sh4*)(vt + d * 24 + g0) = *(const sh4*)&tmp[g0];
  }

  // S^T = K @ Q^T  (A=k rows g, B=q cols h, K-dim = d in 2 steps of 32)
  f4 s = {};
  {
    sh8 kf0 = *(const sh8*)(tb + lg * 208 + 64 + lk * 8);
    sh8 qf0 = *(const sh8*)(tb + lg * 208 + lk * 8);
    s = __builtin_amdgcn_mfma_f32_16x16x32_bf16(kf0, qf0, s, 0, 0, 0);
    sh8 kf1 = *(const sh8*)(tb + lg * 208 + 96 + lk * 8);
    sh8 qf1 = *(const sh8*)(tb + lg * 208 + 32 + lk * 8);
    s = __builtin_amdgcn_mfma_f32_16x16x32_bf16(kf1, qf1, s, 0, 0, 0);
  }

  // scores + bias; softmax over g (regs r + lanes ^16 ^32 share h=lg)
  f4 pbv = *(const f4*)(pos_bias + (size_t)n * 256 + lg * 16 + lk * 4);
  float e[4];
  float m = -1e30f;
#pragma unroll
  for (int r = 0; r < 4; ++r) {
    e[r] = s[r] * 0.125f + pbv[r];
    m = fmaxf(m, e[r]);
  }
  m = fmaxf(m, __shfl_xor(m, 16));
  m = fmaxf(m, __shfl_xor(m, 32));
  float sum = 0.f;
#pragma unroll
  for (int r = 0; r < 4; ++r) {
    e[r] = __expf(e[r] - m);
    sum += e[r];
  }
  sum += __shfl_xor(sum, 16);
  sum += __shfl_xor(sum, 32);
  float inv = 1.0f / sum;
#pragma unroll
  for (int r = 0; r < 4; ++r) e[r] *= inv;

  // redistribute P to 16x16x32 A-layout: lane (h=lg, k=g=lk*8+j), lanes>=32 zero
  sh8 ap;
#pragma unroll
  for (int j = 0; j < 8; ++j) {
    float pv_ = __shfl(e[j & 3], (((lk & 1) * 2 + (j >> 2)) * 16) + lg);
    ap[j] = (lk < 2) ? f2bf(pv_) : (short)0;
  }

  // PV: per d-chunk c, B[k=g][n=d_local=lg] = vT[c*16+lg][ (lk&1)*8 + j ]
  f4 pv[4] = {};
#pragma unroll
  for (int c = 0; c < 4; ++c) {
    sh8 bf = *(const sh8*)(vt + (c * 16 + lg) * 24 + (lk & 1) * 8);
    pv[c] = __builtin_amdgcn_mfma_f32_16x16x32_bf16(ap, bf, pv[c], 0, 0, 0);
  }

  // O[h=(lk*4+r)][d=c*16+lg] -> xcat[t][h*64+d]
  short* dst = xcat + (size_t)t * 2048;
#pragma unroll
  for (int c = 0; c < 4; ++c)
#pragma unroll
    for (int r = 0; r < 4; ++r)
      dst[(lk * 4 + r) * 64 + c * 16 + lg] = f2bf(pv[c][r]);

  // ---- depthwise conv: direct global reads (L2-resident neighbors) --------
#pragma unroll
  for (int it = 0; it < 2; ++it) {
    int w = it * 256 + threadIdx.x;   // 512 = 4 tok x 64 col-chunks
    int tok = w >> 7, co = (w & 127) * 8;
    int tt = t0 + tok, nn = tt & 4095;
    const short* row = qkvx + (size_t)tt * 4096 + 3072 + co;
    sh8 mi = *(const sh8*)row;
    sh8 lo = {}, hi = {};
    if (nn > 0) lo = *(const sh8*)(row - 4096);
    if (nn < 4095) hi = *(const sh8*)(row + 4096);
    sh8 out;
#pragma unroll
    for (int j = 0; j < 8; ++j) {
      float v = dw0[co + j] * bf2f(lo[j]) + dw1[co + j] * bf2f(mi[j]) +
                dw2[co + j] * bf2f(hi[j]) + dwb[co + j];
      out[j] = f2bf(v);
    }
    *(sh8*)(xcat + (size_t)tt * 2048 + 1024 + co) = out;
  }
}

// ---------------------------------------------------------------------------
extern "C" void kernel_launch(void* const* d_in, const int* in_sizes, int n_in,
                              void* d_out, int out_size, void* d_ws,
                              size_t ws_size, hipStream_t stream) {
  const float* x      = (const float*)d_in[0];
  const float* qkv_w  = (const float*)d_in[1];
  const float* qkv_b  = (const float*)d_in[2];
  const float* out_w  = (const float*)d_in[3];
  const float* out_b  = (const float*)d_in[4];
  const float* pos_b  = (const float*)d_in[5];
  const float* conv_w = (const float*)d_in[6];
  const float* conv_b = (const float*)d_in[7];
  const float* pw_w   = (const float*)d_in[8];
  const float* pw_b   = (const float*)d_in[9];
  const float* dw_w   = (const float*)d_in[10];
  const float* dw_b   = (const float*)d_in[11];
  const float* tok_w  = (const float*)d_in[12];
  const float* tok_b  = (const float*)d_in[13];

  const int M = 16384;
  char* ws = (char*)d_ws;
  size_t off = 0;
  auto alloc = [&](size_t bytes) -> void* {
    void* p = ws + off;
    off += (bytes + 255) & ~(size_t)255;
    return p;
  };
  short* xb    = (short*)alloc((size_t)M * 1024 * 2);
  short* wbig  = (short*)alloc((size_t)4096 * 1024 * 2);  // [qkv_w^T | W2^T]
  short* wcatT = (short*)alloc((size_t)1024 * 2048 * 2);
  short* convb = (short*)alloc((size_t)1024 * 1024 * 2);
  short* pwb   = (short*)alloc((size_t)1024 * 1024 * 2);
  short* qkvx  = (short*)alloc((size_t)M * 4096 * 2);
  short* xcat  = (short*)alloc((size_t)M * 2048 * 2);
  float* bias4 = (float*)alloc(4096 * 4);
  float* bcat  = (float*)alloc(1024 * 4);
  float* dw0   = (float*)alloc(1024 * 4);
  float* dw1   = (float*)alloc(1024 * 4);
  float* dw2   = (float*)alloc(1024 * 4);
  float* dwb   = (float*)alloc(1024 * 4);
  (void)ws_size; (void)in_sizes; (void)n_in; (void)out_size;

  // weight prep (consolidated launches)
  cvt3<<<9216, 256, 0, stream>>>(x, conv_w, pw_w, xb, convb, pwb);
  transpose3<<<dim3(32, 32, 5), dim3(32, 8), 0, stream>>>(qkv_w, out_w, tok_w,
                                                          wbig, wcatT);
  prep_misc<<<3072, 256, 0, stream>>>(pw_w, conv_b, pw_b, qkv_b, out_b, tok_b,
                                      dw_w, dw_b, bias4, bcat, dw0, dw1, dw2, dwb);
  // W2^T[o][p] = sum_i pw_w[o][i] * conv_w[p][i] -> rows 3072+ of wbig
  gemm128<1><<<dim3(8, 8), 256, 0, stream>>>(pwb, convb, wbig + (size_t)3072 * 1024,
                                             nullptr, 1024, 1024);

  // fused qkv+conv GEMM: [M,1024] @ [4096,1024]^T -> [M,4096]
  gemm256<1><<<1024, 512, 0, stream>>>(xb, wbig, qkvx, bias4, 1024, 4096, 16);

  // fused MFMA attention + depthwise epilogue
  epilogue<<<4096, 256, 0, stream>>>(qkvx, pos_b, dw0, dw1, dw2, dwb, xcat);

  // out = xcat @ [out_w; tok_w] + (out_b + tok_b)
  gemm256<0><<<256, 512, 0, stream>>>(xcat, wcatT, d_out, bcat, 2048, 1024, 4);
}